// Round 7
// baseline (244.076 us; speedup 1.0000x reference)
//
#include <hip/hip_runtime.h>
#include <hip/hip_bf16.h>

#define EPS 1e-5f

typedef __attribute__((ext_vector_type(8))) short bf16x8;
typedef __attribute__((ext_vector_type(4))) float f32x4;

// ---------------- workspace layout (bytes) ----------------
static constexpr size_t OFF_FT    = 0;             // fT[b][c][n] f32 (1 MB)
static constexpr size_t OFF_W1T   = 1048576;       // W1T[c][o512] f32 (512 KB)
static constexpr size_t OFF_W2B   = 1572864;       // W2 bf16 [128][256] (64 KB)
static constexpr size_t OFF_W3B   = 1638400;       // W3 bf16 [64][128] (16 KB)
static constexpr size_t OFF_S1    = 1654784;
static constexpr size_t OFF_T1    = 1655808;
static constexpr size_t OFF_S2    = 1658368;
static constexpr size_t OFF_T2    = 1658880;
static constexpr size_t OFF_S3    = 1659392;
static constexpr size_t OFF_T3    = 1659648;
static constexpr size_t OFF_ST2   = 1660928;       // gS2[8][128], gQ2[8][128] (4KB+4KB, memset 0)
static constexpr size_t OFF_ST3   = 1669120;       // gS3[8][64], gQ3[8][64] (2KB+2KB, memset 0)
static constexpr size_t OFF_ABT   = 1703936;       // abT[b][n][o512] f32 (2 MB)
static constexpr size_t OFF_H2T   = 4194304;       // h2T bf16 (64 MB); k1 partials overlap (dead before k2)
static constexpr size_t OFF_P1    = OFF_H2T;       // part float2[16][512] (64 KB), k1->k1b only
static constexpr size_t OFF_H3T   = 71303168;      // h3T bf16 (32 MB)

static __device__ inline float bfu2f(unsigned int u16) {
    return __uint_as_float(u16 << 16);
}
static __device__ inline unsigned short f2bfu(float f) {
    unsigned int u = __float_as_uint(f);
    unsigned int r = u + 0x7fffu + ((u >> 16) & 1u);   // RNE
    return (unsigned short)(r >> 16);
}
static __device__ inline unsigned int pkbf(float lo, float hi) {
    __hip_bfloat162 p = __float22bfloat162_rn(make_float2(lo, hi));   // v_cvt_pk_bf16_f32
    return *reinterpret_cast<unsigned int*>(&p);
}

// relu(bn(fv)) for 4 f32 lanes -> 4 packed bf16
static __device__ __forceinline__ uint2 bnpk4(float4 fv, const float* aa, const float* ss, int c) {
    float4 a4 = *(const float4*)(aa + c);
    float4 s4 = *(const float4*)(ss + c);
    float r0 = fmaxf(fmaf(fv.x, s4.x, a4.x), 0.f);
    float r1 = fmaxf(fmaf(fv.y, s4.y, a4.y), 0.f);
    float r2 = fmaxf(fmaf(fv.z, s4.z, a4.z), 0.f);
    float r3 = fmaxf(fmaf(fv.w, s4.w, a4.w), 0.f);
    return make_uint2(pkbf(r0, r1), pkbf(r2, r3));
}
// same but input = 4 bf16 packed in uint2
static __device__ __forceinline__ uint2 bn2pk4(uint2 v, const float* ss, const float* tt, int c) {
    float4 s4 = *(const float4*)(ss + c);
    float4 t4 = *(const float4*)(tt + c);
    float r0 = fmaxf(fmaf(bfu2f(v.x & 0xffffu), s4.x, t4.x), 0.f);
    float r1 = fmaxf(fmaf(bfu2f(v.x >> 16),     s4.y, t4.y), 0.f);
    float r2 = fmaxf(fmaf(bfu2f(v.y & 0xffffu), s4.z, t4.z), 0.f);
    float r3 = fmaxf(fmaf(bfu2f(v.y >> 16),     s4.w, t4.w), 0.f);
    return make_uint2(pkbf(r0, r1), pkbf(r2, r3));
}

// ---------------- K0: pair-mean + transpose -> fT[b][c][n] (128 blocks) ----------------
__global__ __launch_bounds__(256) void k0_pairmean_T(const float* __restrict__ feats,
                                                     float* __restrict__ fT) {
    __shared__ float s[32][65];
    int bx = blockIdx.x;                 // b*32 + nt*4 + ct
    int b = bx >> 5, nt = (bx >> 2) & 7, ct = bx & 3;
    int n0 = nt * 32, c0 = ct * 64;
    int tid = threadIdx.x;
    const float* fb = feats + (size_t)b * 513 * 256;
    #pragma unroll
    for (int k = 0; k < 8; ++k) {
        int idx = tid + k * 256;
        int n = idx >> 6, c = idx & 63;
        const float* r = fb + (size_t)(1 + 2 * (n0 + n)) * 256 + c0 + c;
        s[n][c] = 0.5f * (r[0] + r[256]);
    }
    __syncthreads();
    #pragma unroll
    for (int k = 0; k < 8; ++k) {
        int idx = tid + k * 256;
        int c = idx >> 5, n = idx & 31;
        fT[((size_t)(b * 256) + c0 + c) * 256 + n0 + n] = s[n][c];
    }
}

// ---------------- kt_prep: W1 transpose (f32) + W2/W3 bf16 cast ----------------
__global__ void kt_prep(const float* __restrict__ W1, const float* __restrict__ W2,
                        const float* __restrict__ W3, float* __restrict__ W1T,
                        unsigned short* __restrict__ W2b, unsigned short* __restrict__ W3b) {
    int idx = blockIdx.x * 256 + threadIdx.x;
    if (idx < 131072) {
        int c = idx >> 9, o = idx & 511;
        W1T[idx] = (o < 256) ? W1[(size_t)o * 512 + c] : W1[(size_t)(o - 256) * 512 + 256 + c];
    } else if (idx < 163840) {
        int j = idx - 131072;
        W2b[j] = f2bfu(W2[j]);
    } else if (idx < 172032) {
        int j = idx - 163840;
        W3b[j] = f2bfu(W3[j]);
    }
}

// ---------------- K1: abT[b][n][o512] = sum_c W1T[c][o]*fT[b][c][n] + BN1 partials ----------------
// tile 32o x 64n, grid (16 = b*4+nt, 16 ot) = 256 blocks
__global__ __launch_bounds__(256) void k1_gemm(const float* __restrict__ W1T,
                                               const float* __restrict__ fT,
                                               float* __restrict__ abT,
                                               float2* __restrict__ part) {
    __shared__ float sW[64][36];
    __shared__ float sF[64][68];
    int tid = threadIdx.x;
    int bx = blockIdx.x;
    int b = bx >> 2, n0 = (bx & 3) * 64;
    int o0 = blockIdx.y * 32;
    int og = tid >> 4, jq = tid & 15;
    float acc[2][4] = {};
    for (int c0 = 0; c0 < 256; c0 += 64) {
        #pragma unroll
        for (int k = 0; k < 8; ++k) {
            int idx = tid + k * 256;
            int c = idx >> 5, o = idx & 31;
            sW[c][o] = W1T[(size_t)(c0 + c) * 512 + o0 + o];
        }
        #pragma unroll
        for (int k = 0; k < 16; ++k) {
            int idx = tid + k * 256;
            int c = idx >> 6, n = idx & 63;
            sF[c][n] = fT[((size_t)(b * 256) + c0 + c) * 256 + n0 + n];
        }
        __syncthreads();
        #pragma unroll 8
        for (int c = 0; c < 64; ++c) {
            float4 rv = *(const float4*)&sF[c][jq * 4];
            float2 wv = *(const float2*)&sW[c][og * 2];
            float rr[4] = {rv.x, rv.y, rv.z, rv.w};
            #pragma unroll
            for (int w = 0; w < 4; ++w) {
                acc[0][w] = fmaf(wv.x, rr[w], acc[0][w]);
                acc[1][w] = fmaf(wv.y, rr[w], acc[1][w]);
            }
        }
        __syncthreads();
    }
    // write channel-last
    #pragma unroll
    for (int w = 0; w < 4; ++w) {
        int n = n0 + jq * 4 + w;
        *(float2*)&abT[((size_t)(b * 256) + n) * 512 + o0 + og * 2] =
            make_float2(acc[0][w], acc[1][w]);
    }
    // partials over this block's 64 n
    #pragma unroll
    for (int m = 0; m < 2; ++m) {
        float s = 0.f, q = 0.f;
        #pragma unroll
        for (int w = 0; w < 4; ++w) { float v = acc[m][w]; s += v; q += v * v; }
        #pragma unroll
        for (int off = 8; off; off >>= 1) { s += __shfl_down(s, off); q += __shfl_down(q, off); }
        if (jq == 0) part[(size_t)bx * 512 + o0 + og * 2 + m] = make_float2(s, q);
    }
}

// ---------------- K1b: tiny BN1 param solve from partials ----------------
__global__ void k1b_stats(const float2* __restrict__ part, const float* __restrict__ g1,
                          const float* __restrict__ be1, float* __restrict__ s1,
                          float* __restrict__ t1) {
    __shared__ float Sl[4][512], Ql[4][512];
    int o = threadIdx.x;
    for (int b = 0; b < 4; ++b) {
        float s = 0.f, q = 0.f;
        #pragma unroll
        for (int nt = 0; nt < 4; ++nt) {
            float2 p = part[(size_t)(b * 4 + nt) * 512 + o];
            s += p.x; q += p.y;
        }
        Sl[b][o] = s; Ql[b][o] = q;
    }
    __syncthreads();
    if (o < 256) {
        float msum = 0.f, e2sum = 0.f;
        #pragma unroll
        for (int b = 0; b < 4; ++b) {
            float ma = Sl[b][o] * (1.f / 256.f), mb = Sl[b][o + 256] * (1.f / 256.f);
            msum += ma + mb;
            e2sum += Ql[b][o] * (1.f / 256.f) + Ql[b][o + 256] * (1.f / 256.f) + 2.f * ma * mb;
        }
        float m = msum * 0.25f, e2 = e2sum * 0.25f;
        float var = e2 - m * m;
        float s = g1[o] * rsqrtf(var + EPS);
        s1[o] = s;
        t1[o] = be1[o] - m * s;
    }
}

// ---------------- K2: h2T = W2 @ relu(bn1(a_i + bp_j)) ----------------
// grid (2 jt, 256 i, 4 b); 4 waves 2x2; tile 128o x 128j; K=256, BK=32 double-buffered.
// W2 A-fragments loaded straight from L2 into registers (no LDS staging).
__global__ __launch_bounds__(256) void k2_mfma(const float* __restrict__ abT,
                                               const unsigned short* __restrict__ W2b,
                                               const float* __restrict__ s1,
                                               const float* __restrict__ t1,
                                               unsigned short* __restrict__ h2T,
                                               float* __restrict__ gS2,
                                               float* __restrict__ gQ2) {
    __shared__ __align__(16) char smem[23552];
    float* aaS = (float*)smem;                                 // [256]
    float* ssS = (float*)(smem + 1024);                        // [256]
    float* sS  = (float*)(smem + 2048);                        // [128]
    float* sQ  = (float*)(smem + 2560);                        // [128]
    unsigned short* sB0 = (unsigned short*)(smem + 3072);      // [128][40]
    unsigned short* sB1 = (unsigned short*)(smem + 13312);     // [128][40]
    unsigned short* sT  = (unsigned short*)(smem + 3072);      // [128][72] epilogue (overlaps sB)

    int tid = threadIdx.x;
    int j0 = blockIdx.x * 128, i = blockIdx.y, b = blockIdx.z;

    {
        float av = abT[((size_t)(b * 256 + i)) * 512 + tid];
        float s = s1[tid];
        aaS[tid] = fmaf(av, s, t1[tid]);
        ssS[tid] = s;
    }
    if (tid < 128) { sS[tid] = 0.f; sQ[tid] = 0.f; }
    __syncthreads();

    int lane = tid & 63, wv = tid >> 6;
    int wr = wv >> 1, wc = wv & 1;
    int lo = lane & 15, khi = lane >> 4;
    int jr = tid >> 1, half = tid & 1;

    const float* bpRow = abT + ((size_t)(b * 256 + j0 + jr)) * 512 + 256 + half * 16;
    const unsigned short* wBase = W2b + (wr * 64 + lo) * 256 + khi * 8;

    f32x4 acc[4][4] = {};
    bf16x8 af0, af1, af2, af3;

    // prologue: stage chunk 0 into sB0, preload W chunk 0
    {
        int c = half * 16;
        float4 f0 = *(const float4*)(bpRow + 0);
        float4 f1 = *(const float4*)(bpRow + 4);
        float4 f2 = *(const float4*)(bpRow + 8);
        float4 f3 = *(const float4*)(bpRow + 12);
        uint2 p0 = bnpk4(f0, aaS, ssS, c);
        uint2 p1 = bnpk4(f1, aaS, ssS, c + 4);
        uint2 p2 = bnpk4(f2, aaS, ssS, c + 8);
        uint2 p3 = bnpk4(f3, aaS, ssS, c + 12);
        *(uint4*)(sB0 + jr * 40 + half * 16)     = make_uint4(p0.x, p0.y, p1.x, p1.y);
        *(uint4*)(sB0 + jr * 40 + half * 16 + 8) = make_uint4(p2.x, p2.y, p3.x, p3.y);
    }
    af0 = *(const bf16x8*)(wBase);
    af1 = *(const bf16x8*)(wBase + 4096);
    af2 = *(const bf16x8*)(wBase + 8192);
    af3 = *(const bf16x8*)(wBase + 12288);
    __syncthreads();

    unsigned short* curB = sB0;
    unsigned short* nxtB = sB1;
    #pragma unroll 2
    for (int k = 0; k < 8; ++k) {
        int c0 = k * 32;
        float4 f0, f1, f2, f3;
        bf16x8 an0, an1, an2, an3;
        if (k < 7) {                 // issue next-chunk global loads early
            f0 = *(const float4*)(bpRow + c0 + 32);
            f1 = *(const float4*)(bpRow + c0 + 36);
            f2 = *(const float4*)(bpRow + c0 + 40);
            f3 = *(const float4*)(bpRow + c0 + 44);
            an0 = *(const bf16x8*)(wBase + c0 + 32);
            an1 = *(const bf16x8*)(wBase + 4096 + c0 + 32);
            an2 = *(const bf16x8*)(wBase + 8192 + c0 + 32);
            an3 = *(const bf16x8*)(wBase + 12288 + c0 + 32);
        }
        bf16x8 bfr[4];
        #pragma unroll
        for (int fn = 0; fn < 4; ++fn)
            bfr[fn] = *(const bf16x8*)(curB + (wc * 64 + fn * 16 + lo) * 40 + khi * 8);
        #pragma unroll
        for (int fn = 0; fn < 4; ++fn) {
            acc[0][fn] = __builtin_amdgcn_mfma_f32_16x16x32_bf16(af0, bfr[fn], acc[0][fn], 0, 0, 0);
            acc[1][fn] = __builtin_amdgcn_mfma_f32_16x16x32_bf16(af1, bfr[fn], acc[1][fn], 0, 0, 0);
            acc[2][fn] = __builtin_amdgcn_mfma_f32_16x16x32_bf16(af2, bfr[fn], acc[2][fn], 0, 0, 0);
            acc[3][fn] = __builtin_amdgcn_mfma_f32_16x16x32_bf16(af3, bfr[fn], acc[3][fn], 0, 0, 0);
        }
        if (k < 7) {                 // finish staging next chunk
            int cn = c0 + 32 + half * 16;
            uint2 p0 = bnpk4(f0, aaS, ssS, cn);
            uint2 p1 = bnpk4(f1, aaS, ssS, cn + 4);
            uint2 p2 = bnpk4(f2, aaS, ssS, cn + 8);
            uint2 p3 = bnpk4(f3, aaS, ssS, cn + 12);
            *(uint4*)(nxtB + jr * 40 + half * 16)     = make_uint4(p0.x, p0.y, p1.x, p1.y);
            *(uint4*)(nxtB + jr * 40 + half * 16 + 8) = make_uint4(p2.x, p2.y, p3.x, p3.y);
            af0 = an0; af1 = an1; af2 = an2; af3 = an3;
        }
        __syncthreads();
        unsigned short* t = curB; curB = nxtB; nxtB = t;
    }

    // fused BN2 stats (pre-rounding f32)
    #pragma unroll
    for (int fm = 0; fm < 4; ++fm)
        #pragma unroll
        for (int r = 0; r < 4; ++r) {
            float s = 0.f, q = 0.f;
            #pragma unroll
            for (int fn = 0; fn < 4; ++fn) { float v = acc[fm][fn][r]; s += v; q += v * v; }
            #pragma unroll
            for (int off = 8; off; off >>= 1) { s += __shfl_down(s, off); q += __shfl_down(q, off); }
            if (lo == 0) {
                int o = wr * 64 + fm * 16 + khi * 4 + r;
                atomicAdd(&sS[o], s);
                atomicAdd(&sQ[o], q);
            }
        }

    // epilogue: two-round LDS transpose to channel-last (64 o per round)
    #pragma unroll
    for (int rr = 0; rr < 2; ++rr) {
        __syncthreads();
        if (wr == rr) {
            #pragma unroll
            for (int fm = 0; fm < 4; ++fm)
                #pragma unroll
                for (int fn = 0; fn < 4; ++fn) {
                    int oq = fm * 16 + khi * 4;
                    int j  = wc * 64 + fn * 16 + lo;
                    *(uint2*)(sT + j * 72 + oq) =
                        make_uint2(pkbf(acc[fm][fn][0], acc[fm][fn][1]),
                                   pkbf(acc[fm][fn][2], acc[fm][fn][3]));
                }
        }
        __syncthreads();
        size_t g = (((size_t)(b * 256 + i)) * 256 + j0 + jr) * 128 + rr * 64 + half * 32;
        #pragma unroll
        for (int e = 0; e < 4; ++e) {
            uint4 v = *(const uint4*)(sT + jr * 72 + half * 32 + e * 8);
            *(uint4*)(h2T + g + e * 8) = v;
        }
    }
    if (tid < 128) {
        int slot = (i & 7) * 128;
        atomicAdd(&gS2[slot + tid], sS[tid]);
        atomicAdd(&gQ2[slot + tid], sQ[tid]);
    }
}

// ---------------- bn params from 8-shadow sums ----------------
__global__ void kbnparam(const float* __restrict__ gS, const float* __restrict__ gQ,
                         const float* __restrict__ g, const float* __restrict__ be,
                         float* __restrict__ s, float* __restrict__ t, int C, float invc) {
    int o = threadIdx.x;
    if (o < C) {
        float su = 0.f, qu = 0.f;
        #pragma unroll
        for (int k = 0; k < 8; ++k) { su += gS[k * C + o]; qu += gQ[k * C + o]; }
        float mean = su * invc;
        float var = qu * invc - mean * mean;
        float sc = g[o] * rsqrtf(var + EPS);
        s[o] = sc;
        t[o] = be[o] - mean * sc;
    }
}

// ---------------- K3: h3T = W3 @ relu(bn2(h2T)) ----------------
// grid (2 jt, 256 i, 4 b); 4 waves 1x4 over j; tile 64o x 128j; K=128, BK=32 dbuf.
__global__ __launch_bounds__(256) void k3_mfma(const unsigned short* __restrict__ h2T,
                                               const unsigned short* __restrict__ W3b,
                                               const float* __restrict__ s2,
                                               const float* __restrict__ t2,
                                               unsigned short* __restrict__ h3T,
                                               float* __restrict__ gS3,
                                               float* __restrict__ gQ3) {
    __shared__ __align__(16) char smem[22016];
    float* s2S = (float*)smem;                                 // [128]
    float* t2S = (float*)(smem + 512);                         // [128]
    float* sS  = (float*)(smem + 1024);                        // [64]
    float* sQ  = (float*)(smem + 1280);                        // [64]
    unsigned short* sB0 = (unsigned short*)(smem + 1536);      // [128][40]
    unsigned short* sB1 = (unsigned short*)(smem + 11776);     // [128][40]
    unsigned short* sT  = (unsigned short*)(smem + 1536);      // [128][72] epilogue (overlaps sB)

    int tid = threadIdx.x;
    int j0 = blockIdx.x * 128, i = blockIdx.y, b = blockIdx.z;
    if (tid < 128) { s2S[tid] = s2[tid]; t2S[tid] = t2[tid]; }
    if (tid < 64) { sS[tid] = 0.f; sQ[tid] = 0.f; }
    __syncthreads();

    int lane = tid & 63, wv = tid >> 6;
    int lo = lane & 15, khi = lane >> 4;
    int jr = tid >> 1, half = tid & 1;

    const unsigned short* srcRow = h2T + (((size_t)(b * 256 + i)) * 256 + j0 + jr) * 128 + half * 16;
    const unsigned short* wBase = W3b + lo * 128 + khi * 8;

    f32x4 acc[4][2] = {};
    bf16x8 af0, af1, af2, af3;

    // prologue: stage chunk0, preload W chunk0
    {
        int c = half * 16;
        uint4 v0 = *(const uint4*)(srcRow);
        uint4 v1 = *(const uint4*)(srcRow + 8);
        uint2 p0 = bn2pk4(make_uint2(v0.x, v0.y), s2S, t2S, c);
        uint2 p1 = bn2pk4(make_uint2(v0.z, v0.w), s2S, t2S, c + 4);
        uint2 p2 = bn2pk4(make_uint2(v1.x, v1.y), s2S, t2S, c + 8);
        uint2 p3 = bn2pk4(make_uint2(v1.z, v1.w), s2S, t2S, c + 12);
        *(uint4*)(sB0 + jr * 40 + half * 16)     = make_uint4(p0.x, p0.y, p1.x, p1.y);
        *(uint4*)(sB0 + jr * 40 + half * 16 + 8) = make_uint4(p2.x, p2.y, p3.x, p3.y);
    }
    af0 = *(const bf16x8*)(wBase);
    af1 = *(const bf16x8*)(wBase + 2048);
    af2 = *(const bf16x8*)(wBase + 4096);
    af3 = *(const bf16x8*)(wBase + 6144);
    __syncthreads();

    unsigned short* curB = sB0;
    unsigned short* nxtB = sB1;
    #pragma unroll 2
    for (int k = 0; k < 4; ++k) {
        int c0 = k * 32;
        uint4 v0, v1;
        bf16x8 an0, an1, an2, an3;
        if (k < 3) {
            v0 = *(const uint4*)(srcRow + c0 + 32);
            v1 = *(const uint4*)(srcRow + c0 + 40);
            an0 = *(const bf16x8*)(wBase + c0 + 32);
            an1 = *(const bf16x8*)(wBase + 2048 + c0 + 32);
            an2 = *(const bf16x8*)(wBase + 4096 + c0 + 32);
            an3 = *(const bf16x8*)(wBase + 6144 + c0 + 32);
        }
        bf16x8 bfr[2];
        #pragma unroll
        for (int fn = 0; fn < 2; ++fn)
            bfr[fn] = *(const bf16x8*)(curB + (wv * 32 + fn * 16 + lo) * 40 + khi * 8);
        #pragma unroll
        for (int fn = 0; fn < 2; ++fn) {
            acc[0][fn] = __builtin_amdgcn_mfma_f32_16x16x32_bf16(af0, bfr[fn], acc[0][fn], 0, 0, 0);
            acc[1][fn] = __builtin_amdgcn_mfma_f32_16x16x32_bf16(af1, bfr[fn], acc[1][fn], 0, 0, 0);
            acc[2][fn] = __builtin_amdgcn_mfma_f32_16x16x32_bf16(af2, bfr[fn], acc[2][fn], 0, 0, 0);
            acc[3][fn] = __builtin_amdgcn_mfma_f32_16x16x32_bf16(af3, bfr[fn], acc[3][fn], 0, 0, 0);
        }
        if (k < 3) {
            int cn = c0 + 32 + half * 16;
            uint2 p0 = bn2pk4(make_uint2(v0.x, v0.y), s2S, t2S, cn);
            uint2 p1 = bn2pk4(make_uint2(v0.z, v0.w), s2S, t2S, cn + 4);
            uint2 p2 = bn2pk4(make_uint2(v1.x, v1.y), s2S, t2S, cn + 8);
            uint2 p3 = bn2pk4(make_uint2(v1.z, v1.w), s2S, t2S, cn + 12);
            *(uint4*)(nxtB + jr * 40 + half * 16)     = make_uint4(p0.x, p0.y, p1.x, p1.y);
            *(uint4*)(nxtB + jr * 40 + half * 16 + 8) = make_uint4(p2.x, p2.y, p3.x, p3.y);
            af0 = an0; af1 = an1; af2 = an2; af3 = an3;
        }
        __syncthreads();
        unsigned short* t = curB; curB = nxtB; nxtB = t;
    }

    // fused BN3 stats
    #pragma unroll
    for (int fm = 0; fm < 4; ++fm)
        #pragma unroll
        for (int r = 0; r < 4; ++r) {
            float s = 0.f, q = 0.f;
            #pragma unroll
            for (int fn = 0; fn < 2; ++fn) { float v = acc[fm][fn][r]; s += v; q += v * v; }
            #pragma unroll
            for (int off = 8; off; off >>= 1) { s += __shfl_down(s, off); q += __shfl_down(q, off); }
            if (lo == 0) {
                int o = fm * 16 + khi * 4 + r;
                atomicAdd(&sS[o], s);
                atomicAdd(&sQ[o], q);
            }
        }
    __syncthreads();

    // epilogue: transpose to channel-last (single round, o fits 64)
    #pragma unroll
    for (int fm = 0; fm < 4; ++fm)
        #pragma unroll
        for (int fn = 0; fn < 2; ++fn) {
            int oq = fm * 16 + khi * 4;
            int j  = wv * 32 + fn * 16 + lo;
            *(uint2*)(sT + j * 72 + oq) =
                make_uint2(pkbf(acc[fm][fn][0], acc[fm][fn][1]),
                           pkbf(acc[fm][fn][2], acc[fm][fn][3]));
        }
    __syncthreads();
    {
        size_t g = (((size_t)(b * 256 + i)) * 256 + j0 + jr) * 64 + half * 32;
        #pragma unroll
        for (int e = 0; e < 4; ++e) {
            uint4 v = *(const uint4*)(sT + jr * 72 + half * 32 + e * 8);
            *(uint4*)(h3T + g + e * 8) = v;
        }
    }
    if (tid < 64) {
        int slot = (i & 7) * 64;
        atomicAdd(&gS3[slot + tid], sS[tid]);
        atomicAdd(&gQ3[slot + tid], sQ[tid]);
    }
}

// ---------------- K4: out = W4 @ relu(bn3(h3T)) + b4 ----------------
__global__ __launch_bounds__(256) void k4_final(const unsigned short* __restrict__ h3T,
                                                const float* __restrict__ W4,
                                                const float* __restrict__ s3,
                                                const float* __restrict__ t3,
                                                const float* __restrict__ b4,
                                                float* __restrict__ out) {
    __shared__ __align__(16) char smem[37632];
    float* wS = (float*)smem;            // [64]
    float* sS = (float*)(smem + 256);    // [64]
    float* tS = (float*)(smem + 512);    // [64]
    unsigned short* sL = (unsigned short*)(smem + 768);  // [256][72]
    int tid = threadIdx.x;
    int i = blockIdx.x, b = blockIdx.y;
    if (tid < 64) { wS[tid] = W4[tid]; sS[tid] = s3[tid]; tS[tid] = t3[tid]; }
    const unsigned short* src = h3T + ((size_t)(b * 256 + i)) * 256 * 64;
    #pragma unroll
    for (int e = 0; e < 8; ++e) {
        int f = tid + 256 * e;
        uint4 v = *(const uint4*)(src + f * 8);
        *(uint4*)(sL + (f >> 3) * 72 + (f & 7) * 8) = v;
    }
    __syncthreads();
    float acc = 0.f;
    #pragma unroll
    for (int e = 0; e < 8; ++e) {
        uint4 v = *(const uint4*)(sL + tid * 72 + e * 8);
        unsigned int w[4] = {v.x, v.y, v.z, v.w};
        #pragma unroll
        for (int k = 0; k < 4; ++k) {
            int c = e * 8 + 2 * k;
            float f0 = bfu2f(w[k] & 0xffffu);
            float f1 = bfu2f(w[k] >> 16);
            acc += wS[c] * fmaxf(fmaf(f0, sS[c], tS[c]), 0.f);
            acc += wS[c + 1] * fmaxf(fmaf(f1, sS[c + 1], tS[c + 1]), 0.f);
        }
    }
    out[((size_t)(b * 256 + i)) * 256 + tid] = acc + b4[0];
}

extern "C" void kernel_launch(void* const* d_in, const int* in_sizes, int n_in,
                              void* d_out, int out_size, void* d_ws, size_t ws_size,
                              hipStream_t stream) {
    const float* feats = (const float*)d_in[0];
    const float* W1  = (const float*)d_in[1];
    const float* g1  = (const float*)d_in[3];
    const float* be1 = (const float*)d_in[4];
    const float* W2  = (const float*)d_in[5];
    const float* g2  = (const float*)d_in[7];
    const float* be2 = (const float*)d_in[8];
    const float* W3  = (const float*)d_in[9];
    const float* g3  = (const float*)d_in[11];
    const float* be3 = (const float*)d_in[12];
    const float* W4  = (const float*)d_in[13];
    const float* b4  = (const float*)d_in[14];

    char* ws = (char*)d_ws;
    float* fT   = (float*)(ws + OFF_FT);
    float* W1T  = (float*)(ws + OFF_W1T);
    unsigned short* W2b = (unsigned short*)(ws + OFF_W2B);
    unsigned short* W3b = (unsigned short*)(ws + OFF_W3B);
    float* abT  = (float*)(ws + OFF_ABT);
    float* s1   = (float*)(ws + OFF_S1);
    float* t1   = (float*)(ws + OFF_T1);
    float* gS2  = (float*)(ws + OFF_ST2);
    float* gQ2  = (float*)(ws + OFF_ST2 + 4096);
    float* gS3  = (float*)(ws + OFF_ST3);
    float* gQ3  = (float*)(ws + OFF_ST3 + 2048);
    float* s2 = (float*)(ws + OFF_S2);
    float* t2 = (float*)(ws + OFF_T2);
    float* s3 = (float*)(ws + OFF_S3);
    float* t3 = (float*)(ws + OFF_T3);
    float2* part = (float2*)(ws + OFF_P1);
    unsigned short* h2T = (unsigned short*)(ws + OFF_H2T);
    unsigned short* h3T = (unsigned short*)(ws + OFF_H3T);
    float* out = (float*)d_out;

    hipMemsetAsync(ws + OFF_ST2, 0, 12288, stream);

    k0_pairmean_T<<<128, 256, 0, stream>>>(feats, fT);
    kt_prep<<<672, 256, 0, stream>>>(W1, W2, W3, W1T, W2b, W3b);
    k1_gemm<<<dim3(16, 16), 256, 0, stream>>>(W1T, fT, abT, part);
    k1b_stats<<<1, 512, 0, stream>>>(part, g1, be1, s1, t1);
    k2_mfma<<<dim3(2, 256, 4), 256, 0, stream>>>(abT, W2b, s1, t1, h2T, gS2, gQ2);
    kbnparam<<<1, 128, 0, stream>>>(gS2, gQ2, g2, be2, s2, t2, 128, 1.f / 262144.f);
    k3_mfma<<<dim3(2, 256, 4), 256, 0, stream>>>(h2T, W3b, s2, t2, h3T, gS3, gQ3);
    kbnparam<<<1, 64, 0, stream>>>(gS3, gQ3, g3, be3, s3, t3, 64, 1.f / 262144.f);
    k4_final<<<dim3(256, 4), 256, 0, stream>>>(h3T, W4, s3, t3, b4, out);
}